// Round 3
// baseline (739.131 us; speedup 1.0000x reference)
//
#include <hip/hip_runtime.h>

#define NUM_C 1000
#define NUM_A 512
#define CG 16            // column groups (512 / 32)
#define RG 16            // row groups
#define COLS 32          // columns per block (128 B per row = 1 cache line)
#define PAD 33           // LDS row stride (pad +1 to spread banks)
#define BLK 1024
#define ROWS_PER_STEP (BLK / 8)   // 8 threads per row -> 128 rows per step
#define SLAB (NUM_C * COLS)       // floats per partial slab (32000)

typedef float f32x4 __attribute__((ext_vector_type(4)));

// Workspace layout (bytes):
//   [0,    4096)            counts[1024] (int)
//   [4096, 4096 + 256*128000) partials[256][1000][32] (f32)

__global__ void hist_kernel(const int4* __restrict__ labels4, int* __restrict__ counts, int n4) {
    int i = blockIdx.x * blockDim.x + threadIdx.x;
    int stride = gridDim.x * blockDim.x;
    for (; i < n4; i += stride) {
        int4 lab = labels4[i];
        atomicAdd(&counts[lab.x], 1);
        atomicAdd(&counts[lab.y], 1);
        atomicAdd(&counts[lab.z], 1);
        atomicAdd(&counts[lab.w], 1);
    }
}

// One block per (colgroup, rowgroup). Streams its row range sequentially,
// accumulating into an LDS [NUM_C][PAD] table with DS f32 atomics.
__global__ __launch_bounds__(1024) void accum_kernel(
    const float* __restrict__ F, const int* __restrict__ labels,
    float* __restrict__ partials, int rows_per_rg) {
    extern __shared__ float smem[];   // NUM_C * PAD floats = 132000 B
    int b = blockIdx.x;
    int cg = b & (CG - 1);
    int rg = b >> 4;
    int t = threadIdx.x;

    for (int i = t; i < NUM_C * PAD; i += BLK) smem[i] = 0.f;
    __syncthreads();

    int lane_col = (t & 7) * 4;   // float4 slot within the 32-col slice
    int row_off = t >> 3;         // 0..127
    int row0 = rg * rows_per_rg;

    const float* fptr = F + (size_t)(row0 + row_off) * NUM_A + cg * COLS + lane_col;
    const int* lptr = labels + row0 + row_off;

    int steps = rows_per_rg / ROWS_PER_STEP;   // 128 at N=262144
    for (int s = 0; s < steps; s += 4) {
        int l0 = lptr[0 * ROWS_PER_STEP];
        int l1 = lptr[1 * ROWS_PER_STEP];
        int l2 = lptr[2 * ROWS_PER_STEP];
        int l3 = lptr[3 * ROWS_PER_STEP];
        f32x4 v0 = *(const f32x4*)(fptr + (size_t)0 * ROWS_PER_STEP * NUM_A);
        f32x4 v1 = *(const f32x4*)(fptr + (size_t)1 * ROWS_PER_STEP * NUM_A);
        f32x4 v2 = *(const f32x4*)(fptr + (size_t)2 * ROWS_PER_STEP * NUM_A);
        f32x4 v3 = *(const f32x4*)(fptr + (size_t)3 * ROWS_PER_STEP * NUM_A);

        float* p0 = smem + l0 * PAD + lane_col;
        atomicAdd(p0 + 0, v0.x); atomicAdd(p0 + 1, v0.y);
        atomicAdd(p0 + 2, v0.z); atomicAdd(p0 + 3, v0.w);
        float* p1 = smem + l1 * PAD + lane_col;
        atomicAdd(p1 + 0, v1.x); atomicAdd(p1 + 1, v1.y);
        atomicAdd(p1 + 2, v1.z); atomicAdd(p1 + 3, v1.w);
        float* p2 = smem + l2 * PAD + lane_col;
        atomicAdd(p2 + 0, v2.x); atomicAdd(p2 + 1, v2.y);
        atomicAdd(p2 + 2, v2.z); atomicAdd(p2 + 3, v2.w);
        float* p3 = smem + l3 * PAD + lane_col;
        atomicAdd(p3 + 0, v3.x); atomicAdd(p3 + 1, v3.y);
        atomicAdd(p3 + 2, v3.z); atomicAdd(p3 + 3, v3.w);

        lptr += 4 * ROWS_PER_STEP;
        fptr += (size_t)4 * ROWS_PER_STEP * NUM_A;
    }
    __syncthreads();

    // flush LDS (padded) -> partials (unpadded), coalesced
    float* dst = partials + (size_t)b * SLAB;
    for (int i = t; i < SLAB; i += BLK) {
        int c = i >> 5;
        int col = i & 31;
        dst[i] = smem[c * PAD + col];
    }
}

__global__ __launch_bounds__(256) void finalize_kernel(
    const float* __restrict__ partials, const int* __restrict__ counts,
    float* __restrict__ out) {
    int o = blockIdx.x * blockDim.x + threadIdx.x;
    if (o >= NUM_C * NUM_A) return;
    int c = o >> 9;               // / 512
    int rem = o & (NUM_A - 1);
    int cg = rem >> 5;
    int col = rem & 31;

    const float* p = partials + (size_t)cg * SLAB + c * COLS + col;
    float s = 0.f;
#pragma unroll
    for (int g = 0; g < RG; ++g)
        s += p[(size_t)g * CG * SLAB];

    int cnt = counts[c];
    out[o] = s / (float)(cnt > 0 ? cnt : 1);
}

extern "C" void kernel_launch(void* const* d_in, const int* in_sizes, int n_in,
                              void* d_out, int out_size, void* d_ws, size_t ws_size,
                              hipStream_t stream) {
    const float* features = (const float*)d_in[0];
    const int* labels = (const int*)d_in[1];
    float* out = (float*)d_out;
    int n = in_sizes[1];          // 262144
    int n4 = n / 4;
    int rows_per_rg = n / RG;     // 16384

    char* ws = (char*)d_ws;
    int* counts = (int*)(ws + 0);
    float* partials = (float*)(ws + 4096);

    hipMemsetAsync(counts, 0, 4096, stream);

    hist_kernel<<<256, 256, 0, stream>>>((const int4*)labels, counts, n4);

    static bool attr_set = [] {
        return hipFuncSetAttribute((const void*)accum_kernel,
                                   hipFuncAttributeMaxDynamicSharedMemorySize,
                                   NUM_C * PAD * 4) == hipSuccess;
    }();
    (void)attr_set;

    accum_kernel<<<CG * RG, BLK, NUM_C * PAD * 4, stream>>>(
        features, labels, partials, rows_per_rg);

    finalize_kernel<<<(NUM_C * NUM_A + 255) / 256, 256, 0, stream>>>(
        partials, counts, out);
}

// Round 4
// 128.534 us; speedup vs baseline: 5.7505x; 5.7505x over previous
//
#include <hip/hip_runtime.h>

#define NUM_C 1000
#define NUM_A 512
#define SPLIT 2            // blocks per class in the reduce
#define PRE_BLOCKS 64      // blocks for hist/scatter (privatized)
#define PRE_THREADS 1024

typedef float f32x4 __attribute__((ext_vector_type(4)));

// Workspace layout (bytes):
//   [0,     4096)   counts[1024]  (int)
//   [4096,  8192)   starts[1024]  (int)
//   [8192, 12288)   cursor[1024]  (int)
//   [12288, 12288+4*N)  rowlist[N] (int)       (N=262144 -> 1 MiB)
//   [2 MiB, 2 MiB + SPLIT*1000*512*4)  partials (4 MiB)

// --- K1: privatized histogram -------------------------------------------
__global__ __launch_bounds__(PRE_THREADS) void hist_priv_kernel(
    const int* __restrict__ labels, int* __restrict__ counts, int rows_per_blk) {
    __shared__ int cnt[NUM_C];
    int t = threadIdx.x;
    for (int i = t; i < NUM_C; i += PRE_THREADS) cnt[i] = 0;
    __syncthreads();
    int base = blockIdx.x * rows_per_blk;
    for (int j = t; j < rows_per_blk; j += PRE_THREADS)
        atomicAdd(&cnt[labels[base + j]], 1);
    __syncthreads();
    for (int i = t; i < NUM_C; i += PRE_THREADS)
        if (cnt[i] > 0) atomicAdd(&counts[i], cnt[i]);
}

// --- K2: exclusive scan over 1000 counts --------------------------------
__global__ void scan_kernel(const int* __restrict__ counts, int* __restrict__ starts,
                            int* __restrict__ cursor) {
    __shared__ int buf[1024];
    int t = threadIdx.x;
    int v = (t < NUM_C) ? counts[t] : 0;
    buf[t] = v;
    __syncthreads();
    for (int off = 1; off < 1024; off <<= 1) {
        int x = (t >= off) ? buf[t - off] : 0;
        __syncthreads();
        buf[t] += x;
        __syncthreads();
    }
    int excl = buf[t] - v;
    if (t < NUM_C) {
        starts[t] = excl;
        cursor[t] = excl;
    }
}

// --- K3: privatized scatter ---------------------------------------------
__global__ __launch_bounds__(PRE_THREADS) void scatter_priv_kernel(
    const int* __restrict__ labels, int* __restrict__ cursor,
    int* __restrict__ rowlist, int rows_per_blk) {
    __shared__ int cnt[NUM_C];
    __shared__ int base_l[NUM_C];
    int t = threadIdx.x;
    for (int i = t; i < NUM_C; i += PRE_THREADS) cnt[i] = 0;
    __syncthreads();

    int rbase = blockIdx.x * rows_per_blk;
    // rows_per_blk = 4096, PRE_THREADS = 1024 -> 4 rows per thread
    int l0, l1, l2, l3, s0, s1, s2, s3;
    {
        int r = rbase + t;
        l0 = labels[r + 0 * PRE_THREADS]; s0 = atomicAdd(&cnt[l0], 1);
        l1 = labels[r + 1 * PRE_THREADS]; s1 = atomicAdd(&cnt[l1], 1);
        l2 = labels[r + 2 * PRE_THREADS]; s2 = atomicAdd(&cnt[l2], 1);
        l3 = labels[r + 3 * PRE_THREADS]; s3 = atomicAdd(&cnt[l3], 1);
    }
    __syncthreads();
    for (int i = t; i < NUM_C; i += PRE_THREADS) {
        int c = cnt[i];
        base_l[i] = (c > 0) ? atomicAdd(&cursor[i], c) : 0;
    }
    __syncthreads();
    {
        int r = rbase + t;
        rowlist[base_l[l0] + s0] = r + 0 * PRE_THREADS;
        rowlist[base_l[l1] + s1] = r + 1 * PRE_THREADS;
        rowlist[base_l[l2] + s2] = r + 2 * PRE_THREADS;
        rowlist[base_l[l3] + s3] = r + 3 * PRE_THREADS;
    }
}

// --- K4: gather-reduce, SPLIT blocks per class --------------------------
__global__ __launch_bounds__(256) void reduce_kernel(
    const f32x4* __restrict__ F4,
    const int* __restrict__ starts, const int* __restrict__ counts,
    const int* __restrict__ rowlist, float* __restrict__ partials) {
    int bid = blockIdx.x;
    int c = bid >> 1;          // class
    int s = bid & 1;           // which half of the class rows
    int t = threadIdx.x;
    int half = t >> 7;         // 0/1: row parity within this sub-range
    int q = t & 127;           // float4 column index

    int start = starts[c];
    int cnt = counts[c];
    int lo = (s == 0) ? 0 : (cnt >> 1);
    int hi = (s == 0) ? (cnt >> 1) : cnt;

    f32x4 acc = {0.f, 0.f, 0.f, 0.f};

    int k = lo + half;
    // 16 rows per iteration (8 per half); 8 outstanding 16B loads/thread
    for (; k + 14 < hi; k += 16) {
        int r0 = __builtin_amdgcn_readfirstlane(rowlist[start + k + 0]);
        int r1 = __builtin_amdgcn_readfirstlane(rowlist[start + k + 2]);
        int r2 = __builtin_amdgcn_readfirstlane(rowlist[start + k + 4]);
        int r3 = __builtin_amdgcn_readfirstlane(rowlist[start + k + 6]);
        int r4 = __builtin_amdgcn_readfirstlane(rowlist[start + k + 8]);
        int r5 = __builtin_amdgcn_readfirstlane(rowlist[start + k + 10]);
        int r6 = __builtin_amdgcn_readfirstlane(rowlist[start + k + 12]);
        int r7 = __builtin_amdgcn_readfirstlane(rowlist[start + k + 14]);
        f32x4 v0 = F4[(size_t)r0 * (NUM_A / 4) + q];
        f32x4 v1 = F4[(size_t)r1 * (NUM_A / 4) + q];
        f32x4 v2 = F4[(size_t)r2 * (NUM_A / 4) + q];
        f32x4 v3 = F4[(size_t)r3 * (NUM_A / 4) + q];
        f32x4 v4 = F4[(size_t)r4 * (NUM_A / 4) + q];
        f32x4 v5 = F4[(size_t)r5 * (NUM_A / 4) + q];
        f32x4 v6 = F4[(size_t)r6 * (NUM_A / 4) + q];
        f32x4 v7 = F4[(size_t)r7 * (NUM_A / 4) + q];
        acc += (v0 + v1) + (v2 + v3) + ((v4 + v5) + (v6 + v7));
    }
    for (; k < hi; k += 2) {
        int r = __builtin_amdgcn_readfirstlane(rowlist[start + k]);
        acc += F4[(size_t)r * (NUM_A / 4) + q];
    }

    __shared__ f32x4 sbuf[128];
    if (half == 1) sbuf[q] = acc;
    __syncthreads();
    if (half == 0) {
        acc += sbuf[q];
        f32x4* dst = (f32x4*)(partials + (size_t)bid * NUM_A);
        dst[q] = acc;
    }
}

// --- K5: merge SPLIT partials + divide ----------------------------------
__global__ __launch_bounds__(256) void merge_kernel(
    const float* __restrict__ partials, const int* __restrict__ counts,
    float* __restrict__ out) {
    int o = blockIdx.x * blockDim.x + threadIdx.x;
    if (o >= NUM_C * NUM_A) return;
    int c = o >> 9;
    int rem = o & (NUM_A - 1);
    float s = partials[(size_t)(2 * c + 0) * NUM_A + rem] +
              partials[(size_t)(2 * c + 1) * NUM_A + rem];
    int cnt = counts[c];
    out[o] = s / (float)(cnt > 0 ? cnt : 1);
}

extern "C" void kernel_launch(void* const* d_in, const int* in_sizes, int n_in,
                              void* d_out, int out_size, void* d_ws, size_t ws_size,
                              hipStream_t stream) {
    const float* features = (const float*)d_in[0];
    const int* labels = (const int*)d_in[1];
    float* out = (float*)d_out;
    int n = in_sizes[1];                 // 262144
    int rows_per_blk = n / PRE_BLOCKS;   // 4096

    char* ws = (char*)d_ws;
    int* counts   = (int*)(ws + 0);
    int* starts   = (int*)(ws + 4096);
    int* cursor   = (int*)(ws + 8192);
    int* rowlist  = (int*)(ws + 12288);
    float* partials = (float*)(ws + (2u << 20));

    hipMemsetAsync(counts, 0, 4096, stream);

    hist_priv_kernel<<<PRE_BLOCKS, PRE_THREADS, 0, stream>>>(labels, counts, rows_per_blk);
    scan_kernel<<<1, 1024, 0, stream>>>(counts, starts, cursor);
    scatter_priv_kernel<<<PRE_BLOCKS, PRE_THREADS, 0, stream>>>(labels, cursor, rowlist,
                                                                rows_per_blk);
    reduce_kernel<<<NUM_C * SPLIT, 256, 0, stream>>>((const f32x4*)features, starts,
                                                     counts, rowlist, partials);
    merge_kernel<<<(NUM_C * NUM_A + 255) / 256, 256, 0, stream>>>(partials, counts, out);
}

// Round 5
// 119.430 us; speedup vs baseline: 6.1888x; 1.0762x over previous
//
#include <hip/hip_runtime.h>

#define NUM_C 1000
#define NUM_A 512
#define PRE_BLOCKS 64
#define PRE_THREADS 1024

typedef float f32x4 __attribute__((ext_vector_type(4)));

// Workspace layout (bytes):
//   [0,     4096)   counts[1024]  (int)
//   [4096,  8192)   cursor[1024]  (int)
//   [8192, 12288)   starts[1024]  (int)
//   [12288, 12288+4*N)  rowlist[N] (int)

// --- K1: privatized histogram -------------------------------------------
__global__ __launch_bounds__(PRE_THREADS) void hist_priv_kernel(
    const int4* __restrict__ labels4, int* __restrict__ counts, int n4) {
    __shared__ int cnt[NUM_C];
    int t = threadIdx.x;
    for (int i = t; i < NUM_C; i += PRE_THREADS) cnt[i] = 0;
    __syncthreads();
    int i = blockIdx.x * PRE_THREADS + t;
    int stride = gridDim.x * PRE_THREADS;
    for (; i < n4; i += stride) {
        int4 lab = labels4[i];
        atomicAdd(&cnt[lab.x], 1);
        atomicAdd(&cnt[lab.y], 1);
        atomicAdd(&cnt[lab.z], 1);
        atomicAdd(&cnt[lab.w], 1);
    }
    __syncthreads();
    for (int j = t; j < NUM_C; j += PRE_THREADS)
        if (cnt[j] > 0) atomicAdd(&counts[j], cnt[j]);
}

// --- K2: fused scan + privatized scatter --------------------------------
// Each block recomputes the exclusive scan of counts in LDS, claims its
// per-class region via atomicAdd on the zero-initialized cursor, scatters.
__global__ __launch_bounds__(PRE_THREADS) void scan_scatter_kernel(
    const int* __restrict__ labels, const int* __restrict__ counts,
    int* __restrict__ cursor, int* __restrict__ starts,
    int* __restrict__ rowlist, int rows_per_blk) {
    __shared__ int buf[1024];
    __shared__ int cnt[NUM_C];
    __shared__ int base_l[NUM_C];
    int t = threadIdx.x;
    int v = (t < NUM_C) ? counts[t] : 0;
    buf[t] = v;
    for (int i = t; i < NUM_C; i += PRE_THREADS) cnt[i] = 0;
    __syncthreads();
    for (int off = 1; off < 1024; off <<= 1) {
        int x = (t >= off) ? buf[t - off] : 0;
        __syncthreads();
        buf[t] += x;
        __syncthreads();
    }
    int excl = buf[t] - v;
    if (blockIdx.x == 0 && t < NUM_C) starts[t] = excl;
    buf[t] = excl;                 // buf now holds exclusive prefix
    __syncthreads();

    // local per-class counting (rows_per_blk = 4096 -> 4 rows/thread)
    int rbase = blockIdx.x * rows_per_blk;
    int r = rbase + t;
    int l0 = labels[r + 0 * PRE_THREADS]; int s0 = atomicAdd(&cnt[l0], 1);
    int l1 = labels[r + 1 * PRE_THREADS]; int s1 = atomicAdd(&cnt[l1], 1);
    int l2 = labels[r + 2 * PRE_THREADS]; int s2 = atomicAdd(&cnt[l2], 1);
    int l3 = labels[r + 3 * PRE_THREADS]; int s3 = atomicAdd(&cnt[l3], 1);
    __syncthreads();
    for (int i = t; i < NUM_C; i += PRE_THREADS) {
        int c = cnt[i];
        base_l[i] = (c > 0) ? buf[i] + atomicAdd(&cursor[i], c) : 0;
    }
    __syncthreads();
    rowlist[base_l[l0] + s0] = r + 0 * PRE_THREADS;
    rowlist[base_l[l1] + s1] = r + 1 * PRE_THREADS;
    rowlist[base_l[l2] + s2] = r + 2 * PRE_THREADS;
    rowlist[base_l[l3] + s3] = r + 3 * PRE_THREADS;
}

// --- K3: gather-reduce, one block per class, direct output --------------
// 512 threads = 4 row-slots x 128 float4 quads; unroll 4 -> 16 rows/iter.
// __launch_bounds__(512, 8): VGPR <= 64 -> 4 blocks/CU -> all 1000 blocks
// resident in a single batch (1024 slots).
__global__ __launch_bounds__(512, 8) void reduce_kernel(
    const f32x4* __restrict__ F4,
    const int* __restrict__ starts, const int* __restrict__ counts,
    const int* __restrict__ rowlist, float* __restrict__ out) {
    int c = blockIdx.x;
    int t = threadIdx.x;
    int slot = t >> 7;             // 0..3, uniform within each wave
    int q = t & 127;               // float4 column index

    int start = starts[c];
    int cnt = counts[c];

    f32x4 acc = {0.f, 0.f, 0.f, 0.f};

    int k = slot;
    for (; k + 12 < cnt; k += 16) {
        int r0 = __builtin_amdgcn_readfirstlane(rowlist[start + k + 0]);
        int r1 = __builtin_amdgcn_readfirstlane(rowlist[start + k + 4]);
        int r2 = __builtin_amdgcn_readfirstlane(rowlist[start + k + 8]);
        int r3 = __builtin_amdgcn_readfirstlane(rowlist[start + k + 12]);
        f32x4 v0 = F4[(size_t)r0 * (NUM_A / 4) + q];
        f32x4 v1 = F4[(size_t)r1 * (NUM_A / 4) + q];
        f32x4 v2 = F4[(size_t)r2 * (NUM_A / 4) + q];
        f32x4 v3 = F4[(size_t)r3 * (NUM_A / 4) + q];
        acc += (v0 + v1) + (v2 + v3);
    }
    for (; k < cnt; k += 4) {
        int r = __builtin_amdgcn_readfirstlane(rowlist[start + k]);
        acc += F4[(size_t)r * (NUM_A / 4) + q];
    }

    __shared__ f32x4 sbuf[3][128];
    if (slot > 0) sbuf[slot - 1][q] = acc;
    __syncthreads();
    if (slot == 0) {
        acc += (sbuf[0][q] + sbuf[1][q]) + sbuf[2][q];
        float inv = 1.0f / (float)(cnt > 0 ? cnt : 1);
        f32x4 res = acc * inv;
        ((f32x4*)out)[(size_t)c * (NUM_A / 4) + q] = res;
    }
}

extern "C" void kernel_launch(void* const* d_in, const int* in_sizes, int n_in,
                              void* d_out, int out_size, void* d_ws, size_t ws_size,
                              hipStream_t stream) {
    const float* features = (const float*)d_in[0];
    const int* labels = (const int*)d_in[1];
    float* out = (float*)d_out;
    int n = in_sizes[1];                 // 262144
    int n4 = n / 4;
    int rows_per_blk = n / PRE_BLOCKS;   // 4096

    char* ws = (char*)d_ws;
    int* counts  = (int*)(ws + 0);
    int* cursor  = (int*)(ws + 4096);
    int* starts  = (int*)(ws + 8192);
    int* rowlist = (int*)(ws + 12288);

    hipMemsetAsync(counts, 0, 8192, stream);   // counts + cursor

    hist_priv_kernel<<<PRE_BLOCKS, PRE_THREADS, 0, stream>>>(
        (const int4*)labels, counts, n4);
    scan_scatter_kernel<<<PRE_BLOCKS, PRE_THREADS, 0, stream>>>(
        labels, counts, cursor, starts, rowlist, rows_per_blk);
    reduce_kernel<<<NUM_C, 512, 0, stream>>>(
        (const f32x4*)features, starts, counts, rowlist, out);
}